// Round 2
// baseline (156.225 us; speedup 1.0000x reference)
//
#include <hip/hip_runtime.h>
#include <math.h>

// Problem constants (from reference): N=100000, S=64, Q=50, P=3
#define N_Q 50
#define N_P 3
#define N_S 64
#define ROW 150      // Q*P floats per pauli word
#define ROWP 153     // LDS-padded row (odd stride -> conflict-free lane access)
#define BLK_N 64     // n-rows per block
#define THREADS 256  // 4 waves; wave w handles s in [16w, 16w+16)
#define SCHUNK 16

// ws layout (bytes):
//   [0 .. nblocks*8)        partials (double)  (1563*8 = 12504)
//   [12544 .. +38400)       HP   float[Q][S][3]  (all three normalized head comps)
//   [50944 .. +256)         hrv  float[S]        (smoothed head ratios)
#define WS_HP_OFF 12544
#define WS_HRV_OFF 50944

__device__ __forceinline__ float softplus20(float x) {
    float z = x * 20.0f;
    // stable softplus: max(z,0) + log1p(exp(-|z|))
    return fmaxf(z, 0.0f) + log1pf(expf(-fabsf(z)));
}

__global__ void precompute_kernel(const float* __restrict__ heads_param,
                                  const float* __restrict__ hr_param,
                                  float* __restrict__ HP,
                                  float* __restrict__ hrv) {
    const int tid = threadIdx.x;

    // --- head ratios: first wave only (S == 64 == wave size) ---
    if (tid < N_S) {
        float sp = softplus20(hr_param[tid]);
        float tot = sp;
        #pragma unroll
        for (int off = 32; off; off >>= 1) tot += __shfl_xor(tot, off);
        float hr = sp / fmaxf(tot, 1e-12f);
        hrv[tid] = (hr + 0.001f / (float)N_S) / 1.001f;
    }

    // --- heads: S*Q = 3200 (s,q) cells; keep EXACT reference semantics:
    //     h_p = sp_p / max(sp0+sp1+sp2, EPS).  NOTE: when the EPS clamp fires,
    //     the row does NOT sum to 1 — so all three components must be stored.
    for (int idx = tid; idx < N_S * N_Q; idx += THREADS) {
        int q = idx / N_S;
        int s = idx - q * N_S;
        const float* hp = heads_param + ((size_t)s * N_Q + q) * N_P;
        float sp0 = softplus20(hp[0]);
        float sp1 = softplus20(hp[1]);
        float sp2 = softplus20(hp[2]);
        float denom = fmaxf(sp0 + sp1 + sp2, 1e-12f);
        float* o = HP + ((size_t)q * N_S + s) * 3;
        o[0] = sp0 / denom;
        o[1] = sp1 / denom;
        o[2] = sp2 / denom;
    }
}

__global__ __launch_bounds__(THREADS) void main_kernel(
    const float* __restrict__ A, const float* __restrict__ coeff,
    const float* __restrict__ HP, const float* __restrict__ hrv,
    double* __restrict__ partials, int N) {
    __shared__ float Atile[BLK_N * ROWP];   // 39168 B
    __shared__ float covs[4][BLK_N];        // 1024 B

    const int tid = threadIdx.x;
    const int lane = tid & 63;
    const int wave = tid >> 6;
    const int nbase = blockIdx.x * BLK_N;

    // --- stage A tile (64 rows x 150 floats) via coalesced float2 loads ---
    {
        const int nelem2 = BLK_N * (ROW / 2);  // 4800
        for (int i = tid; i < nelem2; i += THREADS) {
            int row = i / (ROW / 2);
            int col2 = i - row * (ROW / 2);
            int n = nbase + row;
            if (n >= N) n = N - 1;  // clamp: harmless duplicate, masked later
            const float2 v = *(const float2*)(A + (size_t)n * ROW + col2 * 2);
            const int la = row * ROWP + col2 * 2;
            Atile[la + 0] = v.x;
            Atile[la + 1] = v.y;
        }
    }
    __syncthreads();

    // wave-uniform s-chunk base -> SGPR so H reads go down the scalar pipe
    const int s0 = __builtin_amdgcn_readfirstlane(wave * SCHUNK);
    const float* __restrict__ Hw = HP + s0 * 3;

    float prod[SCHUNK];
    #pragma unroll
    for (int i = 0; i < SCHUNK; ++i) prod[i] = 1.0f;

    const float* Arow = Atile + lane * ROWP;

    #pragma unroll 2
    for (int q = 0; q < N_Q; ++q) {
        float a0 = Arow[q * 3 + 0];
        float a1 = Arow[q * 3 + 1];
        float a2 = Arow[q * 3 + 2];
        const float* Hq = Hw + q * (N_S * 3);
        #pragma unroll
        for (int i = 0; i < SCHUNK; ++i) {
            // exact reference dot: h0*a0 + h1*a1 + h2*a2 (no sum-to-1 assumption)
            float d = fmaf(Hq[3 * i + 0], a0,
                     fmaf(Hq[3 * i + 1], a1, Hq[3 * i + 2] * a2));
            prod[i] *= d;
        }
    }

    // ratio-weighted partial sum over this wave's s-chunk
    float acc = 0.0f;
    #pragma unroll
    for (int i = 0; i < SCHUNK; ++i) acc = fmaf(hrv[s0 + i], prod[i], acc);

    covs[wave][lane] = acc;
    __syncthreads();

    if (wave == 0) {
        const int n = nbase + lane;
        float cov = covs[0][lane] + covs[1][lane] + covs[2][lane] + covs[3][lane];
        float term = 0.0f;
        if (n < N) {
            float c = coeff[n];
            term = (c * c) / cov;
        }
        double td = (double)term;
        #pragma unroll
        for (int off = 32; off; off >>= 1) td += __shfl_down(td, off);
        if (lane == 0) partials[blockIdx.x] = td;
    }
}

__global__ void reduce_kernel(const double* __restrict__ partials, int num,
                              float* __restrict__ out) {
    __shared__ double red[4];
    double s = 0.0;
    for (int i = threadIdx.x; i < num; i += THREADS) s += partials[i];
    #pragma unroll
    for (int off = 32; off; off >>= 1) s += __shfl_down(s, off);
    const int wave = threadIdx.x >> 6;
    const int lane = threadIdx.x & 63;
    if (lane == 0) red[wave] = s;
    __syncthreads();
    if (threadIdx.x == 0) out[0] = (float)(red[0] + red[1] + red[2] + red[3]);
}

extern "C" void kernel_launch(void* const* d_in, const int* in_sizes, int n_in,
                              void* d_out, int out_size, void* d_ws, size_t ws_size,
                              hipStream_t stream) {
    const float* A           = (const float*)d_in[0];  // [N, Q, P]
    const float* coeff       = (const float*)d_in[1];  // [N]
    const float* heads_param = (const float*)d_in[2];  // [S, Q, P]
    const float* hr_param    = (const float*)d_in[3];  // [S]
    const int N = in_sizes[1];
    const int nblocks = (N + BLK_N - 1) / BLK_N;

    char* ws = (char*)d_ws;
    double* partials = (double*)ws;
    float* HP  = (float*)(ws + WS_HP_OFF);
    float* hrv = (float*)(ws + WS_HRV_OFF);
    float* out = (float*)d_out;

    precompute_kernel<<<1, THREADS, 0, stream>>>(heads_param, hr_param, HP, hrv);
    main_kernel<<<nblocks, THREADS, 0, stream>>>(A, coeff, HP, hrv, partials, N);
    reduce_kernel<<<1, THREADS, 0, stream>>>(partials, nblocks, out);
}